// Round 11
// baseline (957.887 us; speedup 1.0000x reference)
//
#include <hip/hip_runtime.h>
#include <hip/hip_bf16.h>
#include <math.h>

#define Bq 8
#define Sq 1024
#define Dq 1024
#define Hq 8
#define HDq 64
#define HIDq 512
#define Pq 2048
#define EPSq 1e-6f
#define CAPq 15.0f
#define NCq 16    // chunks per sequence
#define CLq 64    // chunk length

typedef __attribute__((ext_vector_type(8))) short short8;
typedef __attribute__((ext_vector_type(4))) float f32x4v;
typedef __hip_bfloat16 bf16;

__device__ inline void split2(float v, bf16& h, bf16& l) {
  h = __float2bfloat16(v);
  l = __float2bfloat16(v - __bfloat162float(h));
}

__device__ inline float bfs2f(short s) {
  bf16 t = *(const bf16*)&s;
  return __bfloat162float(t);
}

// -------- fused weight split: all 8 weights -> packed hi/lo arenas ----------
__global__ __launch_bounds__(256) void cvtw_all(
    const float* __restrict__ s0, const float* __restrict__ s1,
    const float* __restrict__ s2, const float* __restrict__ s3,
    const float* __restrict__ s4, const float* __restrict__ s5,
    const float* __restrict__ s6, const float* __restrict__ s7,
    bf16* __restrict__ hi, bf16* __restrict__ lo)
{
  int u = blockIdx.x * 256 + threadIdx.x;   // 0 .. 2097151
  const float* src; int segBase;
  if      (u <  524288) { src = s0; segBase = 0;       }
  else if (u <  655360) { src = s1; segBase = 524288;  }
  else if (u <  917504) { src = s2; segBase = 655360;  }
  else if (u < 1179648) { src = s3; segBase = 917504;  }
  else if (u < 1441792) { src = s4; segBase = 1179648; }
  else if (u < 1703936) { src = s5; segBase = 1441792; }
  else if (u < 1966080) { src = s6; segBase = 1703936; }
  else                  { src = s7; segBase = 1966080; }
  float4 v = ((const float4*)src)[u - segBase];
  size_t o = (size_t)u * 4;
  bf16 h, l;
  split2(v.x, h, l); hi[o+0] = h; lo[o+0] = l;
  split2(v.y, h, l); hi[o+1] = h; lo[o+1] = l;
  split2(v.z, h, l); hi[o+2] = h; lo[o+2] = l;
  split2(v.w, h, l); hi[o+3] = h; lo[o+3] = l;
}

// ---------------- LayerNorm over D=1024 -> hi/lo bf16 out ----------------
__global__ __launch_bounds__(256) void ln_kernel(const float* __restrict__ x,
    const float* __restrict__ g, const float* __restrict__ b,
    bf16* __restrict__ yh, bf16* __restrict__ yl)
{
  int row = blockIdx.x;
  int tid = threadIdx.x;
  const float* xr = x + (size_t)row * Dq;
  float v[4]; float s = 0.f, s2 = 0.f;
  #pragma unroll
  for (int i = 0; i < 4; i++) { v[i] = xr[tid + 256*i]; s += v[i]; s2 += v[i]*v[i]; }
  #pragma unroll
  for (int mm = 32; mm > 0; mm >>= 1) { s += __shfl_xor(s, mm, 64); s2 += __shfl_xor(s2, mm, 64); }
  __shared__ float rs[4], rs2[4];
  int lane = tid & 63, wave = tid >> 6;
  if (lane == 0) { rs[wave] = s; rs2[wave] = s2; }
  __syncthreads();
  s  = rs[0] + rs[1] + rs[2] + rs[3];
  s2 = rs2[0] + rs2[1] + rs2[2] + rs2[3];
  float mu  = s * (1.f / Dq);
  float var = s2 * (1.f / Dq) - mu * mu;
  float r = rsqrtf(var + EPSq);
  #pragma unroll
  for (int i = 0; i < 4; i++) {
    int c = tid + 256*i;
    float y = (v[i] - mu) * r * g[c] + b[c];
    bf16 h, l; split2(y, h, l);
    yh[(size_t)row * Dq + c] = h;
    yl[(size_t)row * Dq + c] = l;
  }
}

// ------- bf16x3 MFMA GEMM, 128x(32*NF) tile, BK=32, 256 thr, template -------
// r5/r10 verified schedule (global_load_lds staging, 0 bank conflicts, XOR
// read swizzle, XCD-chunked block swizzle, one vmcnt(0)+barrier per k-step)
// generalized to wider B tiles: NF=5 (gemm1: 16 cols -> 2.0 rounds, no tail)
// and NF=6 (gemm3: 8 cols -> 1.0 round) raise MFMA-per-drain 25-50%.
// LDS/buffer: Ah(4096) Al(4096) Bh(NF*1024) Bl(NF*1024) shorts.
template<int NF>
__device__ __forceinline__ void stageT(short* buf, const short* Ahg,
    const short* Alg, const short* Bhg, const short* Blg,
    int Kd, int k0, int lane, int wave)
{
  int rsub = lane >> 2;                       // row within 16-row slab
  int cs = (lane & 3) ^ ((lane >> 3) & 3);    // pre-swizzled 16B slot
  #pragma unroll
  for (int j = 0; j < 4 + NF; j++) {          // 16+4NF slabs over 4 waves
    int s = wave * (4 + NF) + j;
    const short* srcb; short* dst;
    if (s < 8)                { srcb = Ahg; dst = buf + s * 512; }
    else if (s < 16)          { srcb = Alg; dst = buf + 4096 + (s - 8) * 512; }
    else if (s < 16 + 2 * NF) { srcb = Bhg; dst = buf + 8192 + (s - 16) * 512; }
    else                      { srcb = Blg; dst = buf + 8192 + NF * 1024 + (s - 16 - 2 * NF) * 512; }
    int sIn = (s < 8) ? s : (s < 16) ? (s - 8) : (s < 16 + 2 * NF) ? (s - 16) : (s - 16 - 2 * NF);
    const short* gp = srcb + (size_t)(sIn * 16 + rsub) * Kd + k0 + cs * 8;
    __builtin_amdgcn_global_load_lds(
        (const __attribute__((address_space(1))) void*)gp,
        (__attribute__((address_space(3))) void*)dst, 16, 0, 0);
  }
}

template<int NF>
__global__ __launch_bounds__(256) void gemm_x3T(
    const bf16* __restrict__ Ahi, const bf16* __restrict__ Alo,
    const bf16* __restrict__ Whi, const bf16* __restrict__ Wlo,
    int Kd, int start1, int start2, const float* __restrict__ resid,
    const float* bias0, float* f0, bf16* h0, bf16* l0, int w0, float sc0, int a0,
    const float* bias1, float* f1, bf16* h1, bf16* l1, int w1, float sc1, int a1,
    const float* bias2, float* f2, bf16* h2, bf16* l2, int w2, float sc2, int a2)
{
  extern __shared__ short smem[];   // [2][BUFSH]
  constexpr int BUFSH = 8192 + 2048 * NF;
  int tid = threadIdx.x;
  int lane = tid & 63, wave = tid >> 6;
  int wr = wave >> 1, wc = wave & 1;            // wave tile 64 x (16*NF)

  int gx = gridDim.x;
  int flat = blockIdx.y * gx + blockIdx.x;
  int nb = gx * gridDim.y;
  int chunk = nb >> 3;
  int nid = (flat & 7) * chunk + (flat >> 3);
  int col = nid % gx, row = nid / gx;
  int rowBase = row * 128;
  int colBase = col * (32 * NF);

  const short* Ahg = (const short*)Ahi + (size_t)rowBase * Kd;
  const short* Alg = (const short*)Alo + (size_t)rowBase * Kd;
  const short* Bhg = (const short*)Whi + (size_t)colBase * Kd;
  const short* Blg = (const short*)Wlo + (size_t)colBase * Kd;

  f32x4v acc[4][NF];
  #pragma unroll
  for (int i = 0; i < 4; i++)
    #pragma unroll
    for (int j = 0; j < NF; j++) acc[i][j] = (f32x4v){0.f, 0.f, 0.f, 0.f};

  int fr = lane & 15;
  int cch = lane >> 4;                 // k-chunk 0..3 this lane consumes
  int slotOff = ((cch ^ ((fr >> 1) & 3)) << 3);   // swizzled slot (shorts)
  int nk = Kd >> 5;

  // prologue: DMA tile 0 into buffer 0
  stageT<NF>(smem, Ahg, Alg, Bhg, Blg, Kd, 0, lane, wave);
  asm volatile("s_waitcnt vmcnt(0)" ::: "memory");
  __builtin_amdgcn_s_barrier();

  for (int t = 0; t < nk; ++t) {
    const short* Cb = smem + (t & 1) * BUFSH;
    short* nxt = smem + ((t + 1) & 1) * BUFSH;
    if (t + 1 < nk) stageT<NF>(nxt, Ahg, Alg, Bhg, Blg, Kd, (t + 1) * 32, lane, wave);

    short8 afh[4], afl[4], bfh[NF], bfl[NF];
    #pragma unroll
    for (int mi = 0; mi < 4; mi++) {
      int Ra = (wr * 64 + mi * 16 + fr) * 32;
      afh[mi] = *(const short8*)&Cb[Ra + slotOff];
      afl[mi] = *(const short8*)&Cb[4096 + Ra + slotOff];
    }
    #pragma unroll
    for (int ni = 0; ni < NF; ni++) {
      int Rb = (wc * (16 * NF) + ni * 16 + fr) * 32;
      bfh[ni] = *(const short8*)&Cb[8192 + Rb + slotOff];
      bfl[ni] = *(const short8*)&Cb[8192 + NF * 1024 + Rb + slotOff];
    }
    #pragma unroll
    for (int mi = 0; mi < 4; mi++)
      #pragma unroll
      for (int ni = 0; ni < NF; ni++)
        acc[mi][ni] = __builtin_amdgcn_mfma_f32_16x16x32_bf16(afh[mi], bfh[ni], acc[mi][ni], 0, 0, 0);
    #pragma unroll
    for (int mi = 0; mi < 4; mi++)
      #pragma unroll
      for (int ni = 0; ni < NF; ni++)
        acc[mi][ni] = __builtin_amdgcn_mfma_f32_16x16x32_bf16(afh[mi], bfl[ni], acc[mi][ni], 0, 0, 0);
    #pragma unroll
    for (int mi = 0; mi < 4; mi++)
      #pragma unroll
      for (int ni = 0; ni < NF; ni++)
        acc[mi][ni] = __builtin_amdgcn_mfma_f32_16x16x32_bf16(afl[mi], bfh[ni], acc[mi][ni], 0, 0, 0);

    asm volatile("s_waitcnt vmcnt(0)" ::: "memory");  // next buffer DMA'd
    __builtin_amdgcn_s_barrier();
  }

  int cr = (lane >> 4) * 4;
  int cc = lane & 15;
  // per-fragment segment select: boundaries are multiples of 512 (mult of
  // 16), so a 16-col fragment never straddles; branch is wave-uniform.
  #pragma unroll
  for (int ni = 0; ni < NF; ni++) {
    int colF = colBase + wc * (16 * NF) + ni * 16;
    const float* bias; float* fOut; bf16* hOut; bf16* lOut; int segStart, segW; float sscale; int sact;
    if (colF >= start2)      { bias=bias2; fOut=f2; hOut=h2; lOut=l2; segStart=start2; segW=w2; sscale=sc2; sact=a2; }
    else if (colF >= start1) { bias=bias1; fOut=f1; hOut=h1; lOut=l1; segStart=start1; segW=w1; sscale=sc1; sact=a1; }
    else                     { bias=bias0; fOut=f0; hOut=h0; lOut=l0; segStart=0;      segW=w0; sscale=sc0; sact=a0; }
    int colL = colF + cc - segStart;
    float bv = bias[colL];
    #pragma unroll
    for (int mi = 0; mi < 4; mi++) {
      #pragma unroll
      for (int j = 0; j < 4; j++) {
        int rowO = rowBase + wr * 64 + mi * 16 + cr + j;
        float val = (acc[mi][ni][j] + bv) * sscale;
        if (sact) val = 1.f / (1.f + expf(-val));
        if (resid && segStart == 0) val += resid[(size_t)rowO * segW + colL];
        size_t oidx = (size_t)rowO * segW + colL;
        if (fOut) fOut[oidx] = val;
        if (hOut) {
          bf16 h, l; split2(val, h, l);
          hOut[oidx] = h; lOut[oidx] = l;
        }
      }
    }
  }
}

// ---- FUSED causal conv (K=4) + SiLU + i/f gate dots + softcap ----
__global__ __launch_bounds__(256) void convif_kernel(
    const bf16* __restrict__ xth, const bf16* __restrict__ xtl,
    const float* __restrict__ cw, const float* __restrict__ cb,
    const float* __restrict__ Wi, const float* __restrict__ bi,
    const float* __restrict__ Wf, const float* __restrict__ bf_,
    bf16* __restrict__ xch, bf16* __restrict__ xcl,
    float* __restrict__ ip, float* __restrict__ fp)
{
  int row = blockIdx.x;              // b*S + t
  int tid = threadIdx.x;             // feature chunk: tid*8 .. tid*8+8
  int lane = tid & 63, wave = tid >> 6;
  __shared__ float sRed[4][16];

  size_t idx = (size_t)row * Pq + (size_t)tid * 8;
  const short* hp = (const short*)xth + idx;
  const short* lp = (const short*)xtl + idx;
  short8 ch = *(const short8*)hp;
  short8 cl = *(const short8*)lp;
  float xv[11];
  #pragma unroll
  for (int j = 0; j < 8; j++) xv[3 + j] = bfs2f(ch[j]) + bfs2f(cl[j]);
  if (tid > 0) {
    short8 ph = *(const short8*)(hp - 8);
    short8 pl = *(const short8*)(lp - 8);
    xv[0] = bfs2f(ph[5]) + bfs2f(pl[5]);
    xv[1] = bfs2f(ph[6]) + bfs2f(pl[6]);
    xv[2] = bfs2f(ph[7]) + bfs2f(pl[7]);
  } else {
    xv[0] = xv[1] = xv[2] = 0.f;
  }
  float w0 = cw[0], w1 = cw[1], w2 = cw[2], w3 = cw[3], bb = cb[0];
  float xr[8]; short8 oh, ol;
  #pragma unroll
  for (int j = 0; j < 8; j++) {
    float a = bb + w3 * xv[j + 3] + w2 * xv[j + 2] + w1 * xv[j + 1] + w0 * xv[j];
    float y = a / (1.f + expf(-a));   // silu
    bf16 h, l; split2(y, h, l);
    oh[j] = *(const short*)&h;
    ol[j] = *(const short*)&l;
    xr[j] = __bfloat162float(h) + __bfloat162float(l);  // == value ifk reads
  }
  *(short8*)((short*)xch + idx) = oh;
  *(short8*)((short*)xcl + idx) = ol;

  float pv[16];
  #pragma unroll
  for (int h = 0; h < 16; h++) {
    const float* wr_ = ((h < 8) ? Wi + (size_t)h * Pq
                                : Wf + (size_t)(h - 8) * Pq) + (size_t)tid * 8;
    float4 a = *(const float4*)wr_;
    float4 b2 = *(const float4*)(wr_ + 4);
    pv[h] = xr[0]*a.x + xr[1]*a.y + xr[2]*a.z + xr[3]*a.w
          + xr[4]*b2.x + xr[5]*b2.y + xr[6]*b2.z + xr[7]*b2.w;
  }
  #pragma unroll
  for (int h = 0; h < 16; h++) {
    float v = pv[h];
    #pragma unroll
    for (int m = 32; m > 0; m >>= 1) v += __shfl_xor(v, m, 64);
    pv[h] = v;
  }
  if (lane == 0) {
    #pragma unroll
    for (int h = 0; h < 16; h++) sRed[wave][h] = pv[h];
  }
  __syncthreads();
  if (tid < 16) {
    float v = sRed[0][tid] + sRed[1][tid] + sRed[2][tid] + sRed[3][tid];
    int hh = tid & 7;
    float val = v + ((tid < 8) ? bi[hh] : bf_[hh]);
    val = CAPq * tanhf(val / CAPq);
    if (tid < 8) ip[(size_t)row * Hq + hh] = val;
    else         fp[(size_t)row * Hq + hh] = val;
  }
}

// ===== chunkwise-parallel mLSTM recurrence =====
// --- A: per-chunk scans + KV summary (grid: B*H*NC) ---
__global__ __launch_bounds__(256) void chunkA_kernel(const float* __restrict__ k,
    const float* __restrict__ v, const float* __restrict__ ip,
    const float* __restrict__ fp, float* __restrict__ bg,
    float* __restrict__ FcMc, float* __restrict__ kvg, float* __restrict__ ksumg)
{
  int blk = blockIdx.x;   // bh*NC + c
  int bh = blk >> 4, c = blk & 15;
  int b = bh >> 3, hh = bh & 7;
  int tid = threadIdx.x, lane = tid & 63, wave = tid >> 6;

  __shared__ float sK[64][64], sV[64][64], sW[64];

  size_t base = (size_t)b * Sq * 512 + (size_t)hh * 64 + (size_t)c * CLq * 512;
  int tr = tid >> 4, c4 = (tid & 15) * 4;
  #pragma unroll
  for (int p = 0; p < 4; p++) {
    int t = p * 16 + tr;
    *(float4*)&sK[t][c4] = *(const float4*)(k + base + (size_t)t * 512 + c4);
    *(float4*)&sV[t][c4] = *(const float4*)(v + base + (size_t)t * 512 + c4);
  }
  if (tid < 64) {
    size_t ifb = ((size_t)b * Sq + c * CLq + tid) * Hq + hh;
    float fv = fp[ifb], iv = ip[ifb];
    float cf = fv;                       // inclusive sum scan of f
    #pragma unroll
    for (int off = 1; off < 64; off <<= 1) {
      float t2 = __shfl_up(cf, off, 64);
      if (lane >= off) cf += t2;
    }
    float bs = iv - cf;
    float mx = bs;                       // inclusive max scan
    #pragma unroll
    for (int off = 1; off < 64; off <<= 1) {
      float t2 = __shfl_up(mx, off, 64);
      if (lane >= off) mx = fmaxf(mx, t2);
    }
    float Mc = __shfl(mx, 63, 64);
    bg[(size_t)blk * 64 + tid] = bs;
    sW[tid] = expf(bs - Mc);
    if (tid == 63) { FcMc[blk*2] = cf; FcMc[blk*2+1] = Mc; }
  }
  __syncthreads();
  float acc[16];
  #pragma unroll
  for (int j = 0; j < 16; j++) acc[j] = 0.f;
  for (int s = 0; s < 64; s++) {
    float wv = sW[s] * sV[s][lane];
    #pragma unroll
    for (int j = 0; j < 16; j++) acc[j] += wv * sK[s][wave*16+j];
  }
  float* kvp = kvg + (size_t)blk * 4096 + lane * 64 + wave * 16;
  #pragma unroll
  for (int j = 0; j < 16; j++) kvp[j] = acc[j];
  if (tid < 64) {
    float a = 0.f;
    for (int s = 0; s < 64; s++) a += sW[s] * sK[s][tid];
    ksumg[(size_t)blk * 64 + tid] = a;
  }
}

// --- B: boundary-state propagation, 16 sequential chunk steps (grid: B*H) ---
__global__ __launch_bounds__(1024) void chunkB_kernel(const float* __restrict__ kvg,
    const float* __restrict__ ksumg, const float* __restrict__ FcMc,
    float* __restrict__ boundC, float* __restrict__ boundN, float* __restrict__ boundM)
{
  int bh = blockIdx.x;
  int tid = threadIdx.x;
  int r  = tid >> 4;           // 0..63 (row d)
  int cq = (tid & 15) * 4;     // col quad base
  float4 C4 = {0.f, 0.f, 0.f, 0.f};
  float ne = 1.0f, m = 0.f;    // n0 = ones, m0 = 0
  for (int c = 0; c < NCq; c++) {
    size_t blk = (size_t)bh * NCq + c;
    *(float4*)(boundC + blk * 4096 + r * 64 + cq) = C4;
    if ((tid & 15) == 0) boundN[blk * 64 + r] = ne;
    if (tid == 0)        boundM[blk] = m;
    float Fc = FcMc[blk * 2], Mc = FcMc[blk * 2 + 1];
    float mm = fmaxf(m, Mc);
    float a1 = expf(m - mm), a2 = expf(Mc - mm);
    float4 kv = *(const float4*)(kvg + blk * 4096 + r * 64 + cq);
    C4.x = a1 * C4.x + a2 * kv.x;
    C4.y = a1 * C4.y + a2 * kv.y;
    C4.z = a1 * C4.z + a2 * kv.z;
    C4.w = a1 * C4.w + a2 * kv.w;
    ne = a1 * ne + a2 * ksumg[blk * 64 + r];
    m = Fc + mm;
  }
}

// --- C: intra-chunk attention FUSED with epilogue (o-gate, per-head LN,
//        (hn+skip)*silu(r) -> pdh/pdl). grid: B*H*NC. hs never materialized.
__global__ __launch_bounds__(256) void chunkCE_kernel(const float* __restrict__ q,
    const float* __restrict__ k, const float* __restrict__ v,
    const float* __restrict__ bg, const float* __restrict__ boundC,
    const float* __restrict__ boundN, const float* __restrict__ boundM,
    const float* __restrict__ ov, const float* __restrict__ xs,
    const float* __restrict__ rt, const float* __restrict__ mg,
    const float* __restrict__ mb, bf16* __restrict__ pdh, bf16* __restrict__ pdl)
{
  int blk = blockIdx.x;   // bh*NC + c
  int bh = blk >> 4, c = blk & 15;
  int b = bh >> 3, hh = bh & 7;
  int tid = threadIdx.x, lane = tid & 63, wave = tid >> 6;

  __shared__ float sQ[64][65], sKV[64][65], sS[64][65];
  __shared__ float sB[64], sMr[64], sNin[64];
  __shared__ float sLs[4][64], sLs2[4][64];

  size_t base = (size_t)b * Sq * 512 + (size_t)hh * 64 + (size_t)c * CLq * 512;
  int tr = tid >> 4, c4 = (tid & 15) * 4;
  #pragma unroll
  for (int p = 0; p < 4; p++) {
    int t = p * 16 + tr;
    float4 qv = *(const float4*)(q + base + (size_t)t * 512 + c4);
    float4 kv = *(const float4*)(k + base + (size_t)t * 512 + c4);
    sQ[t][c4+0] = qv.x; sQ[t][c4+1] = qv.y; sQ[t][c4+2] = qv.z; sQ[t][c4+3] = qv.w;
    sKV[t][c4+0] = kv.x; sKV[t][c4+1] = kv.y; sKV[t][c4+2] = kv.z; sKV[t][c4+3] = kv.w;
  }
  float m_in = boundM[blk];
  if (tid < 64) {
    float bs = bg[(size_t)blk * 64 + tid];
    float mx = bs;
    #pragma unroll
    for (int off = 1; off < 64; off <<= 1) {
      float t2 = __shfl_up(mx, off, 64);
      if (lane >= off) mx = fmaxf(mx, t2);
    }
    sB[tid]   = bs;
    sMr[tid]  = fmaxf(m_in, mx);
    sNin[tid] = boundN[(size_t)blk * 64 + tid];
  }
  __syncthreads();

  {
    int t = lane;
    float acc[16];
    #pragma unroll
    for (int j = 0; j < 16; j++) acc[j] = 0.f;
    for (int d = 0; d < 64; d++) {
      float qv = sQ[t][d];
      #pragma unroll
      for (int j = 0; j < 16; j++) acc[j] += qv * sKV[wave*16+j][d];
    }
    float Mr = sMr[t];
    #pragma unroll
    for (int j = 0; j < 16; j++) {
      int s = wave * 16 + j;
      float w = (s <= t) ? expf(sB[s] - Mr) : 0.f;
      sS[t][s] = w * acc[j];
    }
  }
  __syncthreads();
  #pragma unroll
  for (int p = 0; p < 4; p++) {        // restage v over k
    int t = p * 16 + tr;
    float4 vv = *(const float4*)(v + base + (size_t)t * 512 + c4);
    sKV[t][c4+0] = vv.x; sKV[t][c4+1] = vv.y; sKV[t][c4+2] = vv.z; sKV[t][c4+3] = vv.w;
  }
  __syncthreads();

  {
    int t = lane;
    float Mr = sMr[t];
    float bfac = expf(m_in - Mr);
    float den = 0.f;
    for (int d = 0; d < 64; d++) den += sNin[d] * sQ[t][d];
    den *= bfac;
    float num[16];
    #pragma unroll
    for (int j = 0; j < 16; j++) num[j] = 0.f;
    const float* Crow = boundC + (size_t)blk * 4096;
    for (int e = 0; e < 64; e++) {
      float qv = sQ[t][e];
      #pragma unroll
      for (int j = 0; j < 16; j++)
        num[j] += Crow[(size_t)(wave*16+j) * 64 + e] * qv;
    }
    #pragma unroll
    for (int j = 0; j < 16; j++) num[j] *= bfac;
    for (int s = 0; s < 64; s++) {
      float ws = sS[t][s];
      den += ws;
      #pragma unroll
      for (int j = 0; j < 16; j++) num[j] += ws * sKV[s][wave*16+j];
    }
    den = fmaxf(den, 1.0f);

    // ---- fused epilogue ----
    size_t gidx = base + (size_t)t * 512 + (size_t)wave * 16;
    float hv[16];
    float s1 = 0.f, s2 = 0.f;
    #pragma unroll
    for (int j4 = 0; j4 < 4; j4++) {
      float4 og = *(const float4*)(ov + gidx + j4 * 4);
      float o0 = og.x * (num[j4*4+0] / den);
      float o1 = og.y * (num[j4*4+1] / den);
      float o2 = og.z * (num[j4*4+2] / den);
      float o3 = og.w * (num[j4*4+3] / den);
      hv[j4*4+0] = o0; hv[j4*4+1] = o1; hv[j4*4+2] = o2; hv[j4*4+3] = o3;
      s1 += o0 + o1 + o2 + o3;
      s2 += o0*o0 + o1*o1 + o2*o2 + o3*o3;
    }
    sLs[wave][t] = s1; sLs2[wave][t] = s2;
    __syncthreads();
    float S  = sLs[0][t] + sLs[1][t] + sLs[2][t] + sLs[3][t];
    float S2 = sLs2[0][t] + sLs2[1][t] + sLs2[2][t] + sLs2[3][t];
    float mu  = S * (1.f / 64.f);
    float var = S2 * (1.f / 64.f) - mu * mu;
    float rr = rsqrtf(var + EPSq);
    short8 ohv[2], olv[2];
    #pragma unroll
    for (int j4 = 0; j4 < 4; j4++) {
      float4 xsv = *(const float4*)(xs + gidx + j4 * 4);
      float4 rtv = *(const float4*)(rt + gidx + j4 * 4);
      #pragma unroll
      for (int e = 0; e < 4; e++) {
        int j = j4 * 4 + e;
        int d = wave * 16 + j;
        float hn = (hv[j] - mu) * rr * mg[hh * 64 + d] + mb[hh * 64 + d];
        float xsj = (e == 0) ? xsv.x : (e == 1) ? xsv.y : (e == 2) ? xsv.z : xsv.w;
        float rtj = (e == 0) ? rtv.x : (e == 1) ? rtv.y : (e == 2) ? rtv.z : rtv.w;
        float y = (hn + xsj) * (rtj / (1.f + expf(-rtj)));
        bf16 h, l; split2(y, h, l);
        ohv[j >> 3][j & 7] = *(const short*)&h;
        olv[j >> 3][j & 7] = *(const short*)&l;
      }
    }
    *(short8*)((short*)pdh + gidx) = ohv[0];
    *(short8*)((short*)pdh + gidx + 8) = ohv[1];
    *(short8*)((short*)pdl + gidx) = olv[0];
    *(short8*)((short*)pdl + gidx + 8) = olv[1];
  }
}

extern "C" void kernel_launch(void* const* d_in, const int* in_sizes, int n_in,
                              void* d_out, int out_size, void* d_ws, size_t ws_size,
                              hipStream_t stream)
{
  const float* x      = (const float*)d_in[0];
  const float* ln_g   = (const float*)d_in[1];
  const float* ln_b   = (const float*)d_in[2];
  const float* mh_g   = (const float*)d_in[3];
  const float* mh_b   = (const float*)d_in[4];
  const float* W_up_l = (const float*)d_in[5];
  const float* b_up_l = (const float*)d_in[6];
  const float* W_up_r = (const float*)d_in[7];
  const float* b_up_r = (const float*)d_in[8];
  const float* W_down = (const float*)d_in[9];
  const float* b_down = (const float*)d_in[10];
  const float* conv_w = (const float*)d_in[11];
  const float* conv_b = (const float*)d_in[12];
  const float* W_skip = (const float*)d_in[13];
  const float* b_skip = (const float*)d_in[14];
  const float* W_i    = (const float*)d_in[15];
  const float* b_i    = (const float*)d_in[16];
  const float* W_f    = (const float*)d_in[17];
  const float* b_f    = (const float*)d_in[18];
  const float* W_o    = (const float*)d_in[19];
  const float* b_o    = (const float*)d_in[20];
  const float* W_q    = (const float*)d_in[21];
  const float* b_q    = (const float*)d_in[22];
  const float* W_k    = (const float*)d_in[23];
  const float* b_k    = (const float*)d_in[24];
  const float* W_v    = (const float*)d_in[25];
  const float* b_v    = (const float*)d_in[26];
  float* out = (float*)d_out;

  const size_t MB = 1u << 20;
  if (ws_size < 193 * MB) return;

  // allow >64 KB dynamic LDS for the wide-tile GEMMs (one-time, capture-safe)
  static bool attrSet = false;
  if (!attrSet) {
    (void)hipFuncSetAttribute(reinterpret_cast<const void*>(&gemm_x3T<5>),
                              hipFuncAttributeMaxDynamicSharedMemorySize, 73728);
    (void)hipFuncSetAttribute(reinterpret_cast<const void*>(&gemm_x3T<6>),
                              hipFuncAttributeMaxDynamicSharedMemorySize, 81920);
    attrSet = true;
  }

  char* base = (char*)d_ws;
  bf16* whi = (bf16*)base;             // 0..16 MB
  bf16* wlo = (bf16*)(base + 16*MB);   // 16..32 MB
  bf16* xnh = (bf16*)(base + 32*MB);
  bf16* xnl = (bf16*)(base + 48*MB);
  bf16* xth = (bf16*)(base + 64*MB);
  bf16* xtl = (bf16*)(base + 96*MB);
  bf16* xch = (bf16*)(base + 128*MB);
  bf16* xcl = (bf16*)(base + 160*MB);
  // reuse of dead regions:
  float* vb  = (float*)(base + 32*MB); // xn region
  float* ob  = (float*)(base + 48*MB);
  float* xs  = (float*)(base + 64*MB); // xt region
  float* qb  = (float*)(base + 80*MB);
  float* kb  = (float*)(base + 96*MB);
  bf16*  pdh = (bf16*)(base + 112*MB);
  bf16*  pdl = (bf16*)(base + 120*MB);
  // chunkwise-recurrence buffers in dead xc region (after convif):
  float* kvg    = (float*)(base + 128*MB);            // 16 MB
  float* boundC = (float*)(base + 144*MB);            // 16 MB
  float* bg     = (float*)(base + 160*MB);            // 256 KB
  float* ksumg  = (float*)(base + 160*MB + 256*1024); // 256 KB
  float* boundN = (float*)(base + 160*MB + 512*1024); // 256 KB
  float* FcMc   = (float*)(base + 160*MB + 768*1024); // 8 KB
  float* boundM = (float*)(base + 160*MB + 776*1024); // 4 KB
  float* ip  = (float*)(base + 192*MB);
  float* fpb = (float*)(base + 192*MB + 256*1024);
  float* rt  = out;                    // d_out scratch; down GEMM overwrites

  const int Mrows = Bq * Sq;   // 8192
  const int BIG = 1 << 30;

  cvtw_all<<<dim3(8192), dim3(256), 0, stream>>>(
      W_up_l, W_up_r, W_v, W_o, W_skip, W_q, W_k, W_down, whi, wlo);

  ln_kernel<<<dim3(Mrows), dim3(256), 0, stream>>>(x, ln_g, ln_b, xnh, xnl);

  // gemm1: 2560 cols @ 160-wide -> 16x64 = 1024 blocks = exactly 2.0 rounds
  gemm_x3T<5><<<dim3(16, 64), dim3(256), 73728, stream>>>(
      xnh, xnl, whi, wlo, 1024, 2048, BIG, nullptr,
      b_up_l, nullptr, xth, xtl, 2048, 1.f, 0,
      b_up_r, rt, nullptr, nullptr, 512, 1.f, 0,
      nullptr, nullptr, nullptr, nullptr, 1, 1.f, 0);

  // gemm2: 1024 cols @ 128-wide -> 512 blocks = 1.0 round (unchanged)
  gemm_x3T<4><<<dim3(8, 64), dim3(256), 65536, stream>>>(
      xth, xtl, whi + 2621440, wlo + 2621440, 2048, 512, BIG, nullptr,
      b_v, vb, nullptr, nullptr, 512, 1.f, 0,
      b_o, ob, nullptr, nullptr, 512, 1.f, 1,
      nullptr, nullptr, nullptr, nullptr, 1, 1.f, 0);

  convif_kernel<<<dim3(Mrows), dim3(256), 0, stream>>>(
      xth, xtl, conv_w, conv_b, W_i, b_i, W_f, b_f, xch, xcl, ip, fpb);

  // gemm3: 1536 cols @ 192-wide -> 8x64 = 512 blocks = exactly 1.0 round
  gemm_x3T<6><<<dim3(8, 64), dim3(256), 81920, stream>>>(
      xch, xcl, whi + 4718592, wlo + 4718592, 2048, 512, 1024, nullptr,
      b_skip, xs, nullptr, nullptr, 512, 1.f, 0,
      b_q, qb, nullptr, nullptr, 512, 1.f, 0,
      b_k, kb, nullptr, nullptr, 512, 0.125f, 0);
  // xc dead from here; chunk buffers live in its region

  chunkA_kernel<<<dim3(Bq * Hq * NCq), dim3(256), 0, stream>>>(
      kb, vb, ip, fpb, bg, FcMc, kvg, ksumg);
  chunkB_kernel<<<dim3(Bq * Hq), dim3(1024), 0, stream>>>(
      kvg, ksumg, FcMc, boundC, boundN, boundM);
  chunkCE_kernel<<<dim3(Bq * Hq * NCq), dim3(256), 0, stream>>>(
      qb, kb, vb, bg, boundC, boundN, boundM, ob, xs, rt, mh_g, mh_b, pdh, pdl);

  gemm_x3T<4><<<dim3(8, 64), dim3(256), 65536, stream>>>(
      pdh, pdl, whi + 7864320, wlo + 7864320, 512, BIG, BIG, x,
      b_down, out, nullptr, nullptr, 1024, 1.f, 0,
      nullptr, nullptr, nullptr, nullptr, 1, 1.f, 0,
      nullptr, nullptr, nullptr, nullptr, 1, 1.f, 0);
}

// Round 12
// 810.992 us; speedup vs baseline: 1.1811x; 1.1811x over previous
//
#include <hip/hip_runtime.h>
#include <hip/hip_bf16.h>
#include <math.h>

#define Bq 8
#define Sq 1024
#define Dq 1024
#define Hq 8
#define HDq 64
#define HIDq 512
#define Pq 2048
#define EPSq 1e-6f
#define CAPq 15.0f
#define NCq 16    // chunks per sequence
#define CLq 64    // chunk length
// GEMM LDS: 2 buffers x 4 arenas x [128 rows x 32 shorts] linear (64B rows).
// Writes via global_load_lds DMA (linear, conflict-free); reads use per-row
// XOR slot swizzle (slot = chunk ^ ((row>>1)&3)) -> 2-way max (free).
#define ARENA_SH 4096                 // shorts per arena (128*32)
#define BUF_SH   (4 * ARENA_SH)       // shorts per buffer
#define GEMM_SMEM_BYTES (2 * BUF_SH * 2)   // 65536 B

typedef __attribute__((ext_vector_type(8))) short short8;
typedef __attribute__((ext_vector_type(4))) float f32x4v;
typedef __hip_bfloat16 bf16;

__device__ inline void split2(float v, bf16& h, bf16& l) {
  h = __float2bfloat16(v);
  l = __float2bfloat16(v - __bfloat162float(h));
}

__device__ inline float bfs2f(short s) {
  bf16 t = *(const bf16*)&s;
  return __bfloat162float(t);
}

// -------- fused weight split: all 8 weights -> packed hi/lo arenas ----------
__global__ __launch_bounds__(256) void cvtw_all(
    const float* __restrict__ s0, const float* __restrict__ s1,
    const float* __restrict__ s2, const float* __restrict__ s3,
    const float* __restrict__ s4, const float* __restrict__ s5,
    const float* __restrict__ s6, const float* __restrict__ s7,
    bf16* __restrict__ hi, bf16* __restrict__ lo)
{
  int u = blockIdx.x * 256 + threadIdx.x;   // 0 .. 2097151
  const float* src; int segBase;
  if      (u <  524288) { src = s0; segBase = 0;       }
  else if (u <  655360) { src = s1; segBase = 524288;  }
  else if (u <  917504) { src = s2; segBase = 655360;  }
  else if (u < 1179648) { src = s3; segBase = 917504;  }
  else if (u < 1441792) { src = s4; segBase = 1179648; }
  else if (u < 1703936) { src = s5; segBase = 1441792; }
  else if (u < 1966080) { src = s6; segBase = 1703936; }
  else                  { src = s7; segBase = 1966080; }
  float4 v = ((const float4*)src)[u - segBase];
  size_t o = (size_t)u * 4;
  bf16 h, l;
  split2(v.x, h, l); hi[o+0] = h; lo[o+0] = l;
  split2(v.y, h, l); hi[o+1] = h; lo[o+1] = l;
  split2(v.z, h, l); hi[o+2] = h; lo[o+2] = l;
  split2(v.w, h, l); hi[o+3] = h; lo[o+3] = l;
}

// ---------------- LayerNorm over D=1024 -> hi/lo bf16 out ----------------
__global__ __launch_bounds__(256) void ln_kernel(const float* __restrict__ x,
    const float* __restrict__ g, const float* __restrict__ b,
    bf16* __restrict__ yh, bf16* __restrict__ yl)
{
  int row = blockIdx.x;
  int tid = threadIdx.x;
  const float* xr = x + (size_t)row * Dq;
  float v[4]; float s = 0.f, s2 = 0.f;
  #pragma unroll
  for (int i = 0; i < 4; i++) { v[i] = xr[tid + 256*i]; s += v[i]; s2 += v[i]*v[i]; }
  #pragma unroll
  for (int mm = 32; mm > 0; mm >>= 1) { s += __shfl_xor(s, mm, 64); s2 += __shfl_xor(s2, mm, 64); }
  __shared__ float rs[4], rs2[4];
  int lane = tid & 63, wave = tid >> 6;
  if (lane == 0) { rs[wave] = s; rs2[wave] = s2; }
  __syncthreads();
  s  = rs[0] + rs[1] + rs[2] + rs[3];
  s2 = rs2[0] + rs2[1] + rs2[2] + rs2[3];
  float mu  = s * (1.f / Dq);
  float var = s2 * (1.f / Dq) - mu * mu;
  float r = rsqrtf(var + EPSq);
  #pragma unroll
  for (int i = 0; i < 4; i++) {
    int c = tid + 256*i;
    float y = (v[i] - mu) * r * g[c] + b[c];
    bf16 h, l; split2(y, h, l);
    yh[(size_t)row * Dq + c] = h;
    yl[(size_t)row * Dq + c] = l;
  }
}

// ------------- bf16x3 MFMA GEMM, 128x128 tile, BK=32, 256 thr --------------
// r5/r10 verified config: global_load_lds staging (0 bank conflicts), XOR read
// swizzle, XCD-chunked block swizzle, one vmcnt(0)+barrier per k-step.
__device__ __forceinline__ void stage_arena(short* ldsArena, const short* g,
                                            int Kd, int k0, int lane)
{
  int rsub = lane >> 2;                       // 0..15 row within 16-row slab
  int cs = (lane & 3) ^ ((lane >> 3) & 3);    // pre-swizzled 16B slot
  const short* gp = g + (size_t)rsub * Kd + k0 + cs * 8;
  short* lp = ldsArena;
  #pragma unroll
  for (int j = 0; j < 8; j++) {
    __builtin_amdgcn_global_load_lds(
        (const __attribute__((address_space(1))) void*)gp,
        (__attribute__((address_space(3))) void*)lp, 16, 0, 0);
    gp += (size_t)16 * Kd;                    // next 16-row slab
    lp += 512;                                // 16 rows * 32 shorts
  }
}

__global__ __launch_bounds__(256) void gemm_x3(
    const bf16* __restrict__ Ahi, const bf16* __restrict__ Alo,
    const bf16* __restrict__ Whi, const bf16* __restrict__ Wlo,
    int Kd, int start1, int start2, const float* __restrict__ resid,
    const float* bias0, float* f0, bf16* h0, bf16* l0, int w0, float sc0, int a0,
    const float* bias1, float* f1, bf16* h1, bf16* l1, int w1, float sc1, int a1,
    const float* bias2, float* f2, bf16* h2, bf16* l2, int w2, float sc2, int a2)
{
  extern __shared__ short smem[];   // [2][4][ARENA_SH]
  int tid = threadIdx.x;
  int lane = tid & 63, wave = tid >> 6;
  int wr = wave >> 1, wc = wave & 1;            // wave tile 64x64

  int gx = gridDim.x;
  int flat = blockIdx.y * gx + blockIdx.x;
  int nb = gx * gridDim.y;
  int chunk = nb >> 3;
  int nid = (flat & 7) * chunk + (flat >> 3);
  int col = nid % gx, row = nid / gx;
  int rowBase = row * 128;
  int colBase = col * 128;

  const short* Ahg = (const short*)Ahi + (size_t)rowBase * Kd;
  const short* Alg = (const short*)Alo + (size_t)rowBase * Kd;
  const short* Bhg = (const short*)Whi + (size_t)colBase * Kd;
  const short* Blg = (const short*)Wlo + (size_t)colBase * Kd;

  const short* src = (wave == 0) ? Ahg : (wave == 1) ? Alg
                   : (wave == 2) ? Bhg : Blg;
  short* arena0 = smem + wave * ARENA_SH;             // buffer 0, my arena
  short* arena1 = smem + BUF_SH + wave * ARENA_SH;    // buffer 1, my arena

  f32x4v acc[4][4];
  #pragma unroll
  for (int i = 0; i < 4; i++)
    #pragma unroll
    for (int j = 0; j < 4; j++) acc[i][j] = (f32x4v){0.f, 0.f, 0.f, 0.f};

  int fr = lane & 15;
  int cch = lane >> 4;                 // k-chunk 0..3 this lane consumes
  int slotOff = ((cch ^ ((fr >> 1) & 3)) << 3);   // swizzled slot (shorts)
  int nk = Kd >> 5;

  // prologue: DMA tile 0 into buffer 0
  stage_arena(arena0, src, Kd, 0, lane);
  asm volatile("s_waitcnt vmcnt(0)" ::: "memory");
  __builtin_amdgcn_s_barrier();

  for (int t = 0; t < nk; ++t) {
    const short* Cb = smem + (t & 1) * BUF_SH;
    short* nxt = (t & 1) ? arena0 : arena1;
    if (t + 1 < nk) stage_arena(nxt, src, Kd, (t + 1) * 32, lane);

    short8 afh[4], afl[4], bfh[4], bfl[4];
    #pragma unroll
    for (int mi = 0; mi < 4; mi++) {
      int Ra = (wr * 64 + mi * 16 + fr) * 32;
      afh[mi] = *(const short8*)&Cb[0 * ARENA_SH + Ra + slotOff];
      afl[mi] = *(const short8*)&Cb[1 * ARENA_SH + Ra + slotOff];
    }
    #pragma unroll
    for (int ni = 0; ni < 4; ni++) {
      int Rb = (wc * 64 + ni * 16 + fr) * 32;
      bfh[ni] = *(const short8*)&Cb[2 * ARENA_SH + Rb + slotOff];
      bfl[ni] = *(const short8*)&Cb[3 * ARENA_SH + Rb + slotOff];
    }
    #pragma unroll
    for (int mi = 0; mi < 4; mi++)
      #pragma unroll
      for (int ni = 0; ni < 4; ni++)
        acc[mi][ni] = __builtin_amdgcn_mfma_f32_16x16x32_bf16(afh[mi], bfh[ni], acc[mi][ni], 0, 0, 0);
    #pragma unroll
    for (int mi = 0; mi < 4; mi++)
      #pragma unroll
      for (int ni = 0; ni < 4; ni++)
        acc[mi][ni] = __builtin_amdgcn_mfma_f32_16x16x32_bf16(afh[mi], bfl[ni], acc[mi][ni], 0, 0, 0);
    #pragma unroll
    for (int mi = 0; mi < 4; mi++)
      #pragma unroll
      for (int ni = 0; ni < 4; ni++)
        acc[mi][ni] = __builtin_amdgcn_mfma_f32_16x16x32_bf16(afl[mi], bfh[ni], acc[mi][ni], 0, 0, 0);

    asm volatile("s_waitcnt vmcnt(0)" ::: "memory");  // next buffer DMA'd
    __builtin_amdgcn_s_barrier();
  }

  const float* bias; float* fOut; bf16* hOut; bf16* lOut; int segStart, segW; float sscale; int sact;
  if (colBase >= start2)      { bias=bias2; fOut=f2; hOut=h2; lOut=l2; segStart=start2; segW=w2; sscale=sc2; sact=a2; }
  else if (colBase >= start1) { bias=bias1; fOut=f1; hOut=h1; lOut=l1; segStart=start1; segW=w1; sscale=sc1; sact=a1; }
  else                        { bias=bias0; fOut=f0; hOut=h0; lOut=l0; segStart=0;      segW=w0; sscale=sc0; sact=a0; }

  int cr = (lane >> 4) * 4;
  int cc = lane & 15;
  #pragma unroll
  for (int mi = 0; mi < 4; mi++) {
    #pragma unroll
    for (int ni = 0; ni < 4; ni++) {
      int colO  = colBase + wc * 64 + ni * 16 + cc;
      int colL = colO - segStart;
      float bv = bias[colL];
      #pragma unroll
      for (int j = 0; j < 4; j++) {
        int rowO = rowBase + wr * 64 + mi * 16 + cr + j;
        float val = (acc[mi][ni][j] + bv) * sscale;
        if (sact) val = 1.f / (1.f + expf(-val));
        if (resid && segStart == 0) val += resid[(size_t)rowO * segW + colL];
        size_t oidx = (size_t)rowO * segW + colL;
        if (fOut) fOut[oidx] = val;
        if (hOut) {
          bf16 h, l; split2(val, h, l);
          hOut[oidx] = h; lOut[oidx] = l;
        }
      }
    }
  }
}

// ---- FUSED causal conv (K=4) + SiLU + i/f gate dots + softcap ----
// One row per block (256 thr x 8 feats = 2048 = P). Each thread computes
// conv+silu for its 8 contiguous features, then the 16 gate dot partials
// from the SAME registers -- no x re-read, no W staging (W read per-thread
// straight from L2). 256 B LDS only.
__global__ __launch_bounds__(256) void convif_kernel(
    const bf16* __restrict__ xth, const bf16* __restrict__ xtl,
    const float* __restrict__ cw, const float* __restrict__ cb,
    const float* __restrict__ Wi, const float* __restrict__ bi,
    const float* __restrict__ Wf, const float* __restrict__ bf_,
    bf16* __restrict__ xch, bf16* __restrict__ xcl,
    float* __restrict__ ip, float* __restrict__ fp)
{
  int row = blockIdx.x;              // b*S + t
  int tid = threadIdx.x;             // feature chunk: tid*8 .. tid*8+8
  int lane = tid & 63, wave = tid >> 6;
  __shared__ float sRed[4][16];

  size_t idx = (size_t)row * Pq + (size_t)tid * 8;
  const short* hp = (const short*)xth + idx;
  const short* lp = (const short*)xtl + idx;
  short8 ch = *(const short8*)hp;
  short8 cl = *(const short8*)lp;
  float xv[11];
  #pragma unroll
  for (int j = 0; j < 8; j++) xv[3 + j] = bfs2f(ch[j]) + bfs2f(cl[j]);
  if (tid > 0) {
    short8 ph = *(const short8*)(hp - 8);
    short8 pl = *(const short8*)(lp - 8);
    xv[0] = bfs2f(ph[5]) + bfs2f(pl[5]);
    xv[1] = bfs2f(ph[6]) + bfs2f(pl[6]);
    xv[2] = bfs2f(ph[7]) + bfs2f(pl[7]);
  } else {
    xv[0] = xv[1] = xv[2] = 0.f;
  }
  float w0 = cw[0], w1 = cw[1], w2 = cw[2], w3 = cw[3], bb = cb[0];
  float xr[8]; short8 oh, ol;
  #pragma unroll
  for (int j = 0; j < 8; j++) {
    float a = bb + w3 * xv[j + 3] + w2 * xv[j + 2] + w1 * xv[j + 1] + w0 * xv[j];
    float y = a / (1.f + expf(-a));   // silu
    bf16 h, l; split2(y, h, l);
    oh[j] = *(const short*)&h;
    ol[j] = *(const short*)&l;
    xr[j] = __bfloat162float(h) + __bfloat162float(l);  // == value ifk reads
  }
  *(short8*)((short*)xch + idx) = oh;
  *(short8*)((short*)xcl + idx) = ol;

  float pv[16];
  #pragma unroll
  for (int h = 0; h < 16; h++) {
    const float* wr_ = ((h < 8) ? Wi + (size_t)h * Pq
                                : Wf + (size_t)(h - 8) * Pq) + (size_t)tid * 8;
    float4 a = *(const float4*)wr_;
    float4 b2 = *(const float4*)(wr_ + 4);
    pv[h] = xr[0]*a.x + xr[1]*a.y + xr[2]*a.z + xr[3]*a.w
          + xr[4]*b2.x + xr[5]*b2.y + xr[6]*b2.z + xr[7]*b2.w;
  }
  #pragma unroll
  for (int h = 0; h < 16; h++) {
    float v = pv[h];
    #pragma unroll
    for (int m = 32; m > 0; m >>= 1) v += __shfl_xor(v, m, 64);
    pv[h] = v;
  }
  if (lane == 0) {
    #pragma unroll
    for (int h = 0; h < 16; h++) sRed[wave][h] = pv[h];
  }
  __syncthreads();
  if (tid < 16) {
    float v = sRed[0][tid] + sRed[1][tid] + sRed[2][tid] + sRed[3][tid];
    int hh = tid & 7;
    float val = v + ((tid < 8) ? bi[hh] : bf_[hh]);
    val = CAPq * tanhf(val / CAPq);
    if (tid < 8) ip[(size_t)row * Hq + hh] = val;
    else         fp[(size_t)row * Hq + hh] = val;
  }
}

// ===== chunkwise-parallel mLSTM recurrence =====
// --- A: per-chunk scans + KV summary (grid: B*H*NC) ---
__global__ __launch_bounds__(256) void chunkA_kernel(const float* __restrict__ k,
    const float* __restrict__ v, const float* __restrict__ ip,
    const float* __restrict__ fp, float* __restrict__ bg,
    float* __restrict__ FcMc, float* __restrict__ kvg, float* __restrict__ ksumg)
{
  int blk = blockIdx.x;   // bh*NC + c
  int bh = blk >> 4, c = blk & 15;
  int b = bh >> 3, hh = bh & 7;
  int tid = threadIdx.x, lane = tid & 63, wave = tid >> 6;

  __shared__ float sK[64][64], sV[64][64], sW[64];

  size_t base = (size_t)b * Sq * 512 + (size_t)hh * 64 + (size_t)c * CLq * 512;
  int tr = tid >> 4, c4 = (tid & 15) * 4;
  #pragma unroll
  for (int p = 0; p < 4; p++) {
    int t = p * 16 + tr;
    *(float4*)&sK[t][c4] = *(const float4*)(k + base + (size_t)t * 512 + c4);
    *(float4*)&sV[t][c4] = *(const float4*)(v + base + (size_t)t * 512 + c4);
  }
  if (tid < 64) {
    size_t ifb = ((size_t)b * Sq + c * CLq + tid) * Hq + hh;
    float fv = fp[ifb], iv = ip[ifb];
    float cf = fv;                       // inclusive sum scan of f
    #pragma unroll
    for (int off = 1; off < 64; off <<= 1) {
      float t2 = __shfl_up(cf, off, 64);
      if (lane >= off) cf += t2;
    }
    float bs = iv - cf;
    float mx = bs;                       // inclusive max scan
    #pragma unroll
    for (int off = 1; off < 64; off <<= 1) {
      float t2 = __shfl_up(mx, off, 64);
      if (lane >= off) mx = fmaxf(mx, t2);
    }
    float Mc = __shfl(mx, 63, 64);
    bg[(size_t)blk * 64 + tid] = bs;
    sW[tid] = expf(bs - Mc);
    if (tid == 63) { FcMc[blk*2] = cf; FcMc[blk*2+1] = Mc; }
  }
  __syncthreads();
  float acc[16];
  #pragma unroll
  for (int j = 0; j < 16; j++) acc[j] = 0.f;
  for (int s = 0; s < 64; s++) {
    float wv = sW[s] * sV[s][lane];
    #pragma unroll
    for (int j = 0; j < 16; j++) acc[j] += wv * sK[s][wave*16+j];
  }
  float* kvp = kvg + (size_t)blk * 4096 + lane * 64 + wave * 16;
  #pragma unroll
  for (int j = 0; j < 16; j++) kvp[j] = acc[j];
  if (tid < 64) {
    float a = 0.f;
    for (int s = 0; s < 64; s++) a += sW[s] * sK[s][tid];
    ksumg[(size_t)blk * 64 + tid] = a;
  }
}

// --- B: boundary-state propagation, 16 sequential chunk steps (grid: B*H) ---
__global__ __launch_bounds__(1024) void chunkB_kernel(const float* __restrict__ kvg,
    const float* __restrict__ ksumg, const float* __restrict__ FcMc,
    float* __restrict__ boundC, float* __restrict__ boundN, float* __restrict__ boundM)
{
  int bh = blockIdx.x;
  int tid = threadIdx.x;
  int r  = tid >> 4;           // 0..63 (row d)
  int cq = (tid & 15) * 4;     // col quad base
  float4 C4 = {0.f, 0.f, 0.f, 0.f};
  float ne = 1.0f, m = 0.f;    // n0 = ones, m0 = 0
  for (int c = 0; c < NCq; c++) {
    size_t blk = (size_t)bh * NCq + c;
    *(float4*)(boundC + blk * 4096 + r * 64 + cq) = C4;
    if ((tid & 15) == 0) boundN[blk * 64 + r] = ne;
    if (tid == 0)        boundM[blk] = m;
    float Fc = FcMc[blk * 2], Mc = FcMc[blk * 2 + 1];
    float mm = fmaxf(m, Mc);
    float a1 = expf(m - mm), a2 = expf(Mc - mm);
    float4 kv = *(const float4*)(kvg + blk * 4096 + r * 64 + cq);
    C4.x = a1 * C4.x + a2 * kv.x;
    C4.y = a1 * C4.y + a2 * kv.y;
    C4.z = a1 * C4.z + a2 * kv.z;
    C4.w = a1 * C4.w + a2 * kv.w;
    ne = a1 * ne + a2 * ksumg[blk * 64 + r];
    m = Fc + mm;
  }
}

// --- C: intra-chunk attention FUSED with epilogue (o-gate, per-head LN,
//        (hn+skip)*silu(r) -> pdh/pdl). grid: B*H*NC. hs never materialized.
__global__ __launch_bounds__(256) void chunkCE_kernel(const float* __restrict__ q,
    const float* __restrict__ k, const float* __restrict__ v,
    const float* __restrict__ bg, const float* __restrict__ boundC,
    const float* __restrict__ boundN, const float* __restrict__ boundM,
    const float* __restrict__ ov, const float* __restrict__ xs,
    const float* __restrict__ rt, const float* __restrict__ mg,
    const float* __restrict__ mb, bf16* __restrict__ pdh, bf16* __restrict__ pdl)
{
  int blk = blockIdx.x;   // bh*NC + c
  int bh = blk >> 4, c = blk & 15;
  int b = bh >> 3, hh = bh & 7;
  int tid = threadIdx.x, lane = tid & 63, wave = tid >> 6;

  __shared__ float sQ[64][65], sKV[64][65], sS[64][65];
  __shared__ float sB[64], sMr[64], sNin[64];
  __shared__ float sLs[4][64], sLs2[4][64];

  size_t base = (size_t)b * Sq * 512 + (size_t)hh * 64 + (size_t)c * CLq * 512;
  int tr = tid >> 4, c4 = (tid & 15) * 4;
  #pragma unroll
  for (int p = 0; p < 4; p++) {
    int t = p * 16 + tr;
    float4 qv = *(const float4*)(q + base + (size_t)t * 512 + c4);
    float4 kv = *(const float4*)(k + base + (size_t)t * 512 + c4);
    sQ[t][c4+0] = qv.x; sQ[t][c4+1] = qv.y; sQ[t][c4+2] = qv.z; sQ[t][c4+3] = qv.w;
    sKV[t][c4+0] = kv.x; sKV[t][c4+1] = kv.y; sKV[t][c4+2] = kv.z; sKV[t][c4+3] = kv.w;
  }
  float m_in = boundM[blk];
  if (tid < 64) {
    float bs = bg[(size_t)blk * 64 + tid];
    float mx = bs;
    #pragma unroll
    for (int off = 1; off < 64; off <<= 1) {
      float t2 = __shfl_up(mx, off, 64);
      if (lane >= off) mx = fmaxf(mx, t2);
    }
    sB[tid]   = bs;
    sMr[tid]  = fmaxf(m_in, mx);
    sNin[tid] = boundN[(size_t)blk * 64 + tid];
  }
  __syncthreads();

  {
    int t = lane;
    float acc[16];
    #pragma unroll
    for (int j = 0; j < 16; j++) acc[j] = 0.f;
    for (int d = 0; d < 64; d++) {
      float qv = sQ[t][d];
      #pragma unroll
      for (int j = 0; j < 16; j++) acc[j] += qv * sKV[wave*16+j][d];
    }
    float Mr = sMr[t];
    #pragma unroll
    for (int j = 0; j < 16; j++) {
      int s = wave * 16 + j;
      float w = (s <= t) ? expf(sB[s] - Mr) : 0.f;
      sS[t][s] = w * acc[j];
    }
  }
  __syncthreads();
  #pragma unroll
  for (int p = 0; p < 4; p++) {        // restage v over k
    int t = p * 16 + tr;
    float4 vv = *(const float4*)(v + base + (size_t)t * 512 + c4);
    sKV[t][c4+0] = vv.x; sKV[t][c4+1] = vv.y; sKV[t][c4+2] = vv.z; sKV[t][c4+3] = vv.w;
  }
  __syncthreads();

  {
    int t = lane;
    float Mr = sMr[t];
    float bfac = expf(m_in - Mr);
    float den = 0.f;
    for (int d = 0; d < 64; d++) den += sNin[d] * sQ[t][d];
    den *= bfac;
    float num[16];
    #pragma unroll
    for (int j = 0; j < 16; j++) num[j] = 0.f;
    const float* Crow = boundC + (size_t)blk * 4096;
    for (int e = 0; e < 64; e++) {
      float qv = sQ[t][e];
      #pragma unroll
      for (int j = 0; j < 16; j++)
        num[j] += Crow[(size_t)(wave*16+j) * 64 + e] * qv;
    }
    #pragma unroll
    for (int j = 0; j < 16; j++) num[j] *= bfac;
    for (int s = 0; s < 64; s++) {
      float ws = sS[t][s];
      den += ws;
      #pragma unroll
      for (int j = 0; j < 16; j++) num[j] += ws * sKV[s][wave*16+j];
    }
    den = fmaxf(den, 1.0f);

    // ---- fused epilogue ----
    size_t gidx = base + (size_t)t * 512 + (size_t)wave * 16;
    float hv[16];
    float s1 = 0.f, s2 = 0.f;
    #pragma unroll
    for (int j4 = 0; j4 < 4; j4++) {
      float4 og = *(const float4*)(ov + gidx + j4 * 4);
      float o0 = og.x * (num[j4*4+0] / den);
      float o1 = og.y * (num[j4*4+1] / den);
      float o2 = og.z * (num[j4*4+2] / den);
      float o3 = og.w * (num[j4*4+3] / den);
      hv[j4*4+0] = o0; hv[j4*4+1] = o1; hv[j4*4+2] = o2; hv[j4*4+3] = o3;
      s1 += o0 + o1 + o2 + o3;
      s2 += o0*o0 + o1*o1 + o2*o2 + o3*o3;
    }
    sLs[wave][t] = s1; sLs2[wave][t] = s2;
    __syncthreads();
    float S  = sLs[0][t] + sLs[1][t] + sLs[2][t] + sLs[3][t];
    float S2 = sLs2[0][t] + sLs2[1][t] + sLs2[2][t] + sLs2[3][t];
    float mu  = S * (1.f / 64.f);
    float var = S2 * (1.f / 64.f) - mu * mu;
    float rr = rsqrtf(var + EPSq);
    short8 ohv[2], olv[2];
    #pragma unroll
    for (int j4 = 0; j4 < 4; j4++) {
      float4 xsv = *(const float4*)(xs + gidx + j4 * 4);
      float4 rtv = *(const float4*)(rt + gidx + j4 * 4);
      #pragma unroll
      for (int e = 0; e < 4; e++) {
        int j = j4 * 4 + e;
        int d = wave * 16 + j;
        float hn = (hv[j] - mu) * rr * mg[hh * 64 + d] + mb[hh * 64 + d];
        float xsj = (e == 0) ? xsv.x : (e == 1) ? xsv.y : (e == 2) ? xsv.z : xsv.w;
        float rtj = (e == 0) ? rtv.x : (e == 1) ? rtv.y : (e == 2) ? rtv.z : rtv.w;
        float y = (hn + xsj) * (rtj / (1.f + expf(-rtj)));
        bf16 h, l; split2(y, h, l);
        ohv[j >> 3][j & 7] = *(const short*)&h;
        olv[j >> 3][j & 7] = *(const short*)&l;
      }
    }
    *(short8*)((short*)pdh + gidx) = ohv[0];
    *(short8*)((short*)pdh + gidx + 8) = ohv[1];
    *(short8*)((short*)pdl + gidx) = olv[0];
    *(short8*)((short*)pdl + gidx + 8) = olv[1];
  }
}

extern "C" void kernel_launch(void* const* d_in, const int* in_sizes, int n_in,
                              void* d_out, int out_size, void* d_ws, size_t ws_size,
                              hipStream_t stream)
{
  const float* x      = (const float*)d_in[0];
  const float* ln_g   = (const float*)d_in[1];
  const float* ln_b   = (const float*)d_in[2];
  const float* mh_g   = (const float*)d_in[3];
  const float* mh_b   = (const float*)d_in[4];
  const float* W_up_l = (const float*)d_in[5];
  const float* b_up_l = (const float*)d_in[6];
  const float* W_up_r = (const float*)d_in[7];
  const float* b_up_r = (const float*)d_in[8];
  const float* W_down = (const float*)d_in[9];
  const float* b_down = (const float*)d_in[10];
  const float* conv_w = (const float*)d_in[11];
  const float* conv_b = (const float*)d_in[12];
  const float* W_skip = (const float*)d_in[13];
  const float* b_skip = (const float*)d_in[14];
  const float* W_i    = (const float*)d_in[15];
  const float* b_i    = (const float*)d_in[16];
  const float* W_f    = (const float*)d_in[17];
  const float* b_f    = (const float*)d_in[18];
  const float* W_o    = (const float*)d_in[19];
  const float* b_o    = (const float*)d_in[20];
  const float* W_q    = (const float*)d_in[21];
  const float* b_q    = (const float*)d_in[22];
  const float* W_k    = (const float*)d_in[23];
  const float* b_k    = (const float*)d_in[24];
  const float* W_v    = (const float*)d_in[25];
  const float* b_v    = (const float*)d_in[26];
  float* out = (float*)d_out;

  const size_t MB = 1u << 20;
  if (ws_size < 193 * MB) return;

  char* base = (char*)d_ws;
  bf16* whi = (bf16*)base;             // 0..16 MB
  bf16* wlo = (bf16*)(base + 16*MB);   // 16..32 MB
  bf16* xnh = (bf16*)(base + 32*MB);
  bf16* xnl = (bf16*)(base + 48*MB);
  bf16* xth = (bf16*)(base + 64*MB);
  bf16* xtl = (bf16*)(base + 96*MB);
  bf16* xch = (bf16*)(base + 128*MB);
  bf16* xcl = (bf16*)(base + 160*MB);
  // reuse of dead regions:
  float* vb  = (float*)(base + 32*MB); // xn region
  float* ob  = (float*)(base + 48*MB);
  float* xs  = (float*)(base + 64*MB); // xt region
  float* qb  = (float*)(base + 80*MB);
  float* kb  = (float*)(base + 96*MB);
  bf16*  pdh = (bf16*)(base + 112*MB);
  bf16*  pdl = (bf16*)(base + 120*MB);
  // chunkwise-recurrence buffers in dead xc region (after convif):
  float* kvg    = (float*)(base + 128*MB);            // 16 MB
  float* boundC = (float*)(base + 144*MB);            // 16 MB
  float* bg     = (float*)(base + 160*MB);            // 256 KB
  float* ksumg  = (float*)(base + 160*MB + 256*1024); // 256 KB
  float* boundN = (float*)(base + 160*MB + 512*1024); // 256 KB
  float* FcMc   = (float*)(base + 160*MB + 768*1024); // 8 KB
  float* boundM = (float*)(base + 160*MB + 776*1024); // 4 KB
  float* ip  = (float*)(base + 192*MB);
  float* fpb = (float*)(base + 192*MB + 256*1024);
  float* rt  = out;                    // d_out scratch; down GEMM overwrites

  const int Mrows = Bq * Sq;   // 8192
  const int BIG = 1 << 30;

  cvtw_all<<<dim3(8192), dim3(256), 0, stream>>>(
      W_up_l, W_up_r, W_v, W_o, W_skip, W_q, W_k, W_down, whi, wlo);

  ln_kernel<<<dim3(Mrows), dim3(256), 0, stream>>>(x, ln_g, ln_b, xnh, xnl);

  gemm_x3<<<dim3(20, 64), dim3(256), GEMM_SMEM_BYTES, stream>>>(
      xnh, xnl, whi, wlo, 1024, 2048, BIG, nullptr,
      b_up_l, nullptr, xth, xtl, 2048, 1.f, 0,
      b_up_r, rt, nullptr, nullptr, 512, 1.f, 0,
      nullptr, nullptr, nullptr, nullptr, 1, 1.f, 0);

  gemm_x3<<<dim3(8, 64), dim3(256), GEMM_SMEM_BYTES, stream>>>(
      xth, xtl, whi + 2621440, wlo + 2621440, 2048, 512, BIG, nullptr,
      b_v, vb, nullptr, nullptr, 512, 1.f, 0,
      b_o, ob, nullptr, nullptr, 512, 1.f, 1,
      nullptr, nullptr, nullptr, nullptr, 1, 1.f, 0);

  convif_kernel<<<dim3(Mrows), dim3(256), 0, stream>>>(
      xth, xtl, conv_w, conv_b, W_i, b_i, W_f, b_f, xch, xcl, ip, fpb);

  gemm_x3<<<dim3(12, 64), dim3(256), GEMM_SMEM_BYTES, stream>>>(
      xch, xcl, whi + 4718592, wlo + 4718592, 2048, 512, 1024, nullptr,
      b_skip, xs, nullptr, nullptr, 512, 1.f, 0,
      b_q, qb, nullptr, nullptr, 512, 1.f, 0,
      b_k, kb, nullptr, nullptr, 512, 0.125f, 0);
  // xc dead from here; chunk buffers live in its region

  chunkA_kernel<<<dim3(Bq * Hq * NCq), dim3(256), 0, stream>>>(
      kb, vb, ip, fpb, bg, FcMc, kvg, ksumg);
  chunkB_kernel<<<dim3(Bq * Hq), dim3(1024), 0, stream>>>(
      kvg, ksumg, FcMc, boundC, boundN, boundM);
  chunkCE_kernel<<<dim3(Bq * Hq * NCq), dim3(256), 0, stream>>>(
      qb, kb, vb, bg, boundC, boundN, boundM, ob, xs, rt, mh_g, mh_b, pdh, pdl);

  gemm_x3<<<dim3(8, 64), dim3(256), GEMM_SMEM_BYTES, stream>>>(
      pdh, pdl, whi + 7864320, wlo + 7864320, 512, BIG, BIG, x,
      b_down, out, nullptr, nullptr, 1024, 1.f, 0,
      nullptr, nullptr, nullptr, nullptr, 1, 1.f, 0,
      nullptr, nullptr, nullptr, nullptr, 1, 1.f, 0);
}